// Round 2
// 1003.518 us; speedup vs baseline: 1.0747x; 1.0747x over previous
//
#include <hip/hip_runtime.h>
#include <hip/hip_bf16.h>
#include <cstdint>

// Problem constants
constexpr int Bb  = 2;
constexpr int Ss  = 2048;
constexpr int HID = 2048;
constexpr int NH  = 16;
constexpr int NKV = 2;
constexpr int HD  = 128;
constexpr int Mrows = Bb * Ss;                 // 4096 rows for projections
constexpr float SCALE = 0.08838834764831845f;  // 1/sqrt(128)

typedef __bf16 bf16_t;
typedef __attribute__((ext_vector_type(8))) __bf16 bf16x8;
typedef __attribute__((ext_vector_type(4))) __bf16 bf16x4;
typedef __attribute__((ext_vector_type(4))) float f32x4;

static __device__ __forceinline__ f32x4 mfma16(bf16x8 a, bf16x8 b, f32x4 c) {
  return __builtin_amdgcn_mfma_f32_16x16x32_bf16(a, b, c, 0, 0, 0);
}

// ---- async 128x32 bf16 tile staging via global_load_lds (16B per lane) ------
// LDS layout [row][32] contiguous; chunk c: row=c>>2, kcol=(c&3)*8.
// dst byte offset = c*16 = wave-uniform base + lane*16  (required HW pattern)
static __device__ __forceinline__ void stage_async(bf16_t* lds, const bf16_t* src,
                                                   int ld, int tid) {
#pragma unroll
  for (int it = 0; it < 2; ++it) {
    int c = tid + it * 256;
    int row = c >> 2, kc = c & 3;
    __builtin_amdgcn_global_load_lds(
        (const __attribute__((address_space(1))) void*)(src + (size_t)row * ld + kc * 8),
        (__attribute__((address_space(3))) void*)(lds + c * 8), 16, 0, 0);
  }
}

// ---------------- per-wave MFMA compute, templated wave shape ----------------
template <int IM, int JM>
static __device__ __forceinline__ void wave_mma(const bf16_t* As, const bf16_t* Bs,
                                                f32x4 (&acc)[IM][JM], int wm, int wn,
                                                int lane) {
  const int q = lane >> 4, r = lane & 15;
  bf16x8 a[IM], b[JM];
#pragma unroll
  for (int i = 0; i < IM; ++i)
    a[i] = *(const bf16x8*)(As + (wm + i * 16 + r) * 32 + q * 8);
#pragma unroll
  for (int j = 0; j < JM; ++j)
    b[j] = *(const bf16x8*)(Bs + (wn + j * 16 + r) * 32 + q * 8);
#pragma unroll
  for (int i = 0; i < IM; ++i)
#pragma unroll
    for (int j = 0; j < JM; ++j)
      acc[i][j] = mfma16(a[i], b[j], acc[i][j]);
}

// ------------------------------ small kernels --------------------------------
__global__ void cvt_bf16_kernel(const float* __restrict__ in, bf16_t* __restrict__ out) {
  size_t i = ((size_t)blockIdx.x * 256 + threadIdx.x) * 8;
  float4 a = *(const float4*)(in + i);
  float4 b = *(const float4*)(in + i + 4);
  bf16x8 v;
  v[0] = (__bf16)a.x; v[1] = (__bf16)a.y; v[2] = (__bf16)a.z; v[3] = (__bf16)a.w;
  v[4] = (__bf16)b.x; v[5] = (__bf16)b.y; v[6] = (__bf16)b.z; v[7] = (__bf16)b.w;
  *(bf16x8*)(out + i) = v;
}

__global__ void zero_kernel(float* __restrict__ p) {
  p[(size_t)blockIdx.x * 256 + threadIdx.x] = 0.0f;
}

// ------------- fused QKV projection + bias + RoPE/transpose epilogue ---------
// A: (4096, 2048) bf16 = hs. B: (2560, 2048) bf16 = [Wq; Wk; Wv].
// cols [0,2048): q -> rope -> q_bf (B,NH,S,HD)
// cols [2048,2304): k -> rope -> k_bf (B,NKV,S,HD)
// cols [2304,2560): v -> transposed -> v_t (B,NKV,HD,S)
// Wave partition: each wave 32 rows x 128 cols so RoPE partner (d^64) is
// acc[i][j^4][t] in the SAME lane (no cross-wave exchange needed).
__global__ __launch_bounds__(256) void proj_kernel(
    const bf16_t* __restrict__ A, const bf16_t* __restrict__ Bt,
    const float* __restrict__ bq, const float* __restrict__ bk,
    const float* __restrict__ bv, const float* __restrict__ cosb,
    const float* __restrict__ sinb, bf16_t* __restrict__ q_bf,
    bf16_t* __restrict__ k_bf, bf16_t* __restrict__ v_t) {
  __shared__ __align__(16) bf16_t As[128 * 32];
  __shared__ __align__(16) bf16_t Bs[128 * 32];
  const int tid = threadIdx.x;
  const int bx = blockIdx.x;
  const int m0 = blockIdx.y * 128, n0 = bx * 128;
  const int lane = tid & 63, w = tid >> 6;
  const int wm = w * 32;  // 32 rows x 128 cols per wave
  const int q = lane >> 4, r = lane & 15;
  f32x4 acc[2][8];
#pragma unroll
  for (int i = 0; i < 2; ++i)
#pragma unroll
    for (int j = 0; j < 8; ++j) acc[i][j] = (f32x4){0.f, 0.f, 0.f, 0.f};
  const bf16_t* Ap = A + (size_t)m0 * HID;
  const bf16_t* Bp = Bt + (size_t)n0 * HID;
  for (int k0 = 0; k0 < HID; k0 += 32) {
    stage_async(As, Ap + k0, HID, tid);
    stage_async(Bs, Bp + k0, HID, tid);
    __syncthreads();
    wave_mma<2, 8>(As, Bs, acc, wm, 0, lane);
    __syncthreads();
  }
  // block-uniform output mode
  const float* bias_base;
  int mode;  // 0=q, 1=k, 2=v
  int hh;
  if (bx < 16) { mode = 0; hh = bx; bias_base = bq + n0; }
  else if (bx < 18) { mode = 1; hh = bx - 16; bias_base = bk + (bx - 16) * 128; }
  else { mode = 2; hh = bx - 18; bias_base = bv + (bx - 18) * 128; }
  float bias_j[8];
#pragma unroll
  for (int j = 0; j < 8; ++j) bias_j[j] = bias_base[j * 16 + r];
  float e[2][8][4];
#pragma unroll
  for (int i = 0; i < 2; ++i)
#pragma unroll
    for (int j = 0; j < 8; ++j)
#pragma unroll
      for (int t = 0; t < 4; ++t) e[i][j][t] = acc[i][j][t] + bias_j[j];

  if (mode == 2) {
    // V: store transposed (B,NKV,HD,S); 4 consecutive s per lane -> 8B packs
#pragma unroll
    for (int i = 0; i < 2; ++i) {
      int s_base = m0 + wm + i * 16 + q * 4;
      int bI = s_base >> 11, s = s_base & 2047;
#pragma unroll
      for (int j = 0; j < 8; ++j) {
        int d = j * 16 + r;
        bf16x4 pk;
#pragma unroll
        for (int t = 0; t < 4; ++t) pk[t] = (__bf16)e[i][j][t];
        *(bf16x4*)(v_t + ((size_t)(bI * NKV + hh) * HD + d) * Ss + s) = pk;
      }
    }
  } else {
    bf16_t* dst_base = (mode == 0) ? q_bf : k_bf;
    const int nhv = (mode == 0) ? NH : NKV;
#pragma unroll
    for (int i = 0; i < 2; ++i) {
#pragma unroll
      for (int t = 0; t < 4; ++t) {
        int s_glob = m0 + wm + i * 16 + q * 4 + t;
        int bI = s_glob >> 11, s = s_glob & 2047;
        const float* cp = cosb + ((size_t)bI * Ss + s) * HD;
        const float* sp = sinb + ((size_t)bI * Ss + s) * HD;
        bf16_t* dst = dst_base + ((size_t)(bI * nhv + hh) * Ss + s) * HD;
#pragma unroll
        for (int j = 0; j < 8; ++j) {
          int d = j * 16 + r;
          float c = cp[d], sn = sp[d];
          float p = e[i][j ^ 4][t];
          float o = e[i][j][t] * c + ((j < 4) ? -p : p) * sn;
          dst[d] = (__bf16)o;
        }
      }
    }
  }
}

// -------- pass 1: rowsums of exp(q@k^T * SCALE), NO P write ------------------
// lower-triangle tiles only; accumulates per-row sums into rowsum (atomic).
__global__ __launch_bounds__(256) void qs_kernel(const bf16_t* __restrict__ qb,
                                                 const bf16_t* __restrict__ kb,
                                                 float* __restrict__ rowsum) {
  const int tj = blockIdx.x, ti = blockIdx.y;
  if (tj > ti) return;
  const int bh = blockIdx.z;
  const int b = bh >> 4, h = bh & 15, kv = h >> 3;
  __shared__ __align__(16) bf16_t As[128 * 32];
  __shared__ __align__(16) bf16_t Bs[128 * 32];
  __shared__ float rs[128];
  const int tid = threadIdx.x;
  if (tid < 128) rs[tid] = 0.0f;
  const int lane = tid & 63, w = tid >> 6;
  const int wm = (w >> 1) * 64, wn = (w & 1) * 64;
  const int q = lane >> 4, r = lane & 15;
  f32x4 acc[4][4];
#pragma unroll
  for (int i = 0; i < 4; ++i)
#pragma unroll
    for (int j = 0; j < 4; ++j) acc[i][j] = (f32x4){0.f, 0.f, 0.f, 0.f};
  const bf16_t* Ap = qb + (size_t)bh * Ss * HD + (size_t)ti * 128 * HD;
  const bf16_t* Bp = kb + (size_t)(b * NKV + kv) * Ss * HD + (size_t)tj * 128 * HD;
#pragma unroll
  for (int k0 = 0; k0 < HD; k0 += 32) {
    stage_async(As, Ap + k0, HD, tid);
    stage_async(Bs, Bp + k0, HD, tid);
    __syncthreads();
    wave_mma<4, 4>(As, Bs, acc, wm, wn, lane);
    __syncthreads();
  }
  const bool diag = (ti == tj);
  float rp[4][4];
#pragma unroll
  for (int i = 0; i < 4; ++i)
#pragma unroll
    for (int t = 0; t < 4; ++t) rp[i][t] = 0.0f;
#pragma unroll
  for (int i = 0; i < 4; ++i) {
#pragma unroll
    for (int t = 0; t < 4; ++t) {
      int row_l = wm + i * 16 + q * 4 + t;
#pragma unroll
      for (int j = 0; j < 4; ++j) {
        int col_l = wn + j * 16 + r;
        float ev = (diag && col_l > row_l) ? 0.0f : __expf(acc[i][j][t] * SCALE);
        rp[i][t] += ev;
      }
    }
  }
  // reduce row partials across the 16 lanes sharing q (lane = q*16 + r)
#pragma unroll
  for (int off = 1; off < 16; off <<= 1)
#pragma unroll
    for (int i = 0; i < 4; ++i)
#pragma unroll
      for (int t = 0; t < 4; ++t) rp[i][t] += __shfl_xor(rp[i][t], off, 64);
  if (r == 0) {
#pragma unroll
    for (int i = 0; i < 4; ++i)
#pragma unroll
      for (int t = 0; t < 4; ++t)
        atomicAdd(&rs[wm + i * 16 + q * 4 + t], rp[i][t]);
  }
  __syncthreads();
  if (tid < 128)
    atomicAdd(rowsum + (size_t)bh * Ss + (size_t)ti * 128 + tid, rs[tid]);
}

// -------- pass 2: recompute QK, write normalized attn ONCE, fused PV ---------
// One block per (row-strip mt, head bh). Q strip cached in registers.
// LDS: Ks (32KB, shared between K and V staging) + padded P (34KB) -> 2 blk/CU.
// Upper-triangle zero-fill folded in (anti-balances compute-tile count).
__global__ __launch_bounds__(256, 2) void spv_kernel(
    const bf16_t* __restrict__ qb, const bf16_t* __restrict__ kb,
    const bf16_t* __restrict__ vt, const float* __restrict__ rowsum,
    float* __restrict__ attn, bf16_t* __restrict__ ao) {
  const int mt = blockIdx.y;
  const int bh = blockIdx.z;
  const int b = bh >> 4, h = bh & 15, kv = h >> 3;
  __shared__ __align__(16) bf16_t Ks[4][128 * 32];  // K or V slices (time-shared)
  __shared__ __align__(16) bf16_t Ps[128 * 136];    // P transpose buf, +8 pad
  __shared__ float inv_s[128];
  const int tid = threadIdx.x;
  if (tid < 128)
    inv_s[tid] = 1.0f / rowsum[(size_t)bh * Ss + (size_t)mt * 128 + tid];
  const int lane = tid & 63, w = tid >> 6;
  const int wm = (w >> 1) * 64, wn = (w & 1) * 64;
  const int q = lane >> 4, r = lane & 15;

  // ---- Q strip (128 x 128) -> registers, staged through LDS for coalescing
  const bf16_t* Qp = qb + (size_t)bh * Ss * HD + (size_t)mt * 128 * HD;
#pragma unroll
  for (int s = 0; s < 4; ++s) stage_async(Ks[s], Qp + s * 32, HD, tid);
  __syncthreads();  // Q staged + inv_s visible
  bf16x8 aq[4][4];
#pragma unroll
  for (int s = 0; s < 4; ++s)
#pragma unroll
    for (int i = 0; i < 4; ++i)
      aq[s][i] = *(const bf16x8*)(Ks[s] + (wm + i * 16 + r) * 32 + q * 8);
  float inv_my[4][4];
#pragma unroll
  for (int i = 0; i < 4; ++i)
#pragma unroll
    for (int t = 0; t < 4; ++t)
      inv_my[i][t] = inv_s[wm + i * 16 + q * 4 + t];
  __syncthreads();  // Ks free for K staging

  const bf16_t* Kp = kb + (size_t)(b * NKV + kv) * Ss * HD;
  const bf16_t* Vp = vt + (size_t)(b * NKV + kv) * HD * Ss;
  float* Arow = attn + ((size_t)bh * Ss + (size_t)mt * 128) * Ss;

  f32x4 acc2[4][4];
#pragma unroll
  for (int i = 0; i < 4; ++i)
#pragma unroll
    for (int j = 0; j < 4; ++j) acc2[i][j] = (f32x4){0.f, 0.f, 0.f, 0.f};

  for (int kt = 0; kt <= mt; ++kt) {
    // ---- stage K tile (4 x 128x32 slices)
#pragma unroll
    for (int s = 0; s < 4; ++s)
      stage_async(Ks[s], Kp + (size_t)kt * 128 * HD + s * 32, HD, tid);
    __syncthreads();
    // ---- QK^T for this tile (Q from registers)
    f32x4 acc[4][4];
#pragma unroll
    for (int i = 0; i < 4; ++i)
#pragma unroll
      for (int j = 0; j < 4; ++j) acc[i][j] = (f32x4){0.f, 0.f, 0.f, 0.f};
#pragma unroll
    for (int s = 0; s < 4; ++s) {
      bf16x8 bfr[4];
#pragma unroll
      for (int j = 0; j < 4; ++j)
        bfr[j] = *(const bf16x8*)(Ks[s] + (wn + j * 16 + r) * 32 + q * 8);
#pragma unroll
      for (int i = 0; i < 4; ++i)
#pragma unroll
        for (int j = 0; j < 4; ++j)
          acc[i][j] = mfma16(aq[s][i], bfr[j], acc[i][j]);
    }
    // ---- exp * inv, write final attn fp32, and P bf16 -> LDS (for transpose)
    // (no barrier needed here: Ks reads above are fenced by the next barrier
    //  before V staging overwrites Ks; prev-iter Ps reads ended at loop tail)
    const bool diag = (kt == mt);
#pragma unroll
    for (int i = 0; i < 4; ++i) {
#pragma unroll
      for (int t = 0; t < 4; ++t) {
        int row_l = wm + i * 16 + q * 4 + t;
        float inv = inv_my[i][t];
        float* orow = Arow + (size_t)row_l * Ss + kt * 128;
#pragma unroll
        for (int j = 0; j < 4; ++j) {
          int col_l = wn + j * 16 + r;
          float ev = (diag && col_l > row_l)
                         ? 0.0f
                         : __expf(acc[i][j][t] * SCALE) * inv;
          orow[col_l] = ev;
          Ps[row_l * 136 + col_l] = (__bf16)ev;
        }
      }
    }
    __syncthreads();  // Ps complete; QK's Ks reads done -> Ks free for V
    // ---- stage V tile: Ks[s] = [d=0..127][32 k-cols] from v_t (B,NKV,HD,S)
#pragma unroll
    for (int s = 0; s < 4; ++s)
      stage_async(Ks[s], Vp + kt * 128 + s * 32, Ss, tid);
    __syncthreads();
    // ---- PV accumulate (A = P from LDS transpose buffer, B = V slices)
#pragma unroll
    for (int s = 0; s < 4; ++s) {
      bf16x8 ap[4], bv4[4];
#pragma unroll
      for (int i = 0; i < 4; ++i)
        ap[i] = *(const bf16x8*)(Ps + (wm + i * 16 + r) * 136 + s * 32 + q * 8);
#pragma unroll
      for (int j = 0; j < 4; ++j)
        bv4[j] = *(const bf16x8*)(Ks[s] + (wn + j * 16 + r) * 32 + q * 8);
#pragma unroll
      for (int i = 0; i < 4; ++i)
#pragma unroll
        for (int j = 0; j < 4; ++j)
          acc2[i][j] = mfma16(ap[i], bv4[j], acc2[i][j]);
    }
    __syncthreads();  // before next kt overwrites Ks/Ps
  }

  // ---- zero-fill strictly-upper region: cols [kmax, 2048) of 128 rows
  const int kmax = (mt + 1) * 128;
  const int width = Ss - kmax;
  if (width > 0) {
    const float4 z4 = {0.f, 0.f, 0.f, 0.f};
    for (int rr = 0; rr < 128; ++rr) {
      float* zp = Arow + (size_t)rr * Ss + kmax;
      for (int cc = tid * 4; cc < width; cc += 1024) *(float4*)(zp + cc) = z4;
    }
  }
  // ---- epilogue: attn_out (B,S,NH*HD) bf16
#pragma unroll
  for (int i = 0; i < 4; ++i) {
#pragma unroll
    for (int t = 0; t < 4; ++t) {
      int row = mt * 128 + wm + i * 16 + q * 4 + t;
#pragma unroll
      for (int j = 0; j < 4; ++j) {
        int col = wn + j * 16 + r;
        ao[(((size_t)b * Ss + row) * NH + h) * HD + col] = (__bf16)acc2[i][j][t];
      }
    }
  }
}

// ------------------------ out = attn_out @ Wo^T ------------------------------
__global__ __launch_bounds__(256) void out_kernel(const bf16_t* __restrict__ A,
                                                  const bf16_t* __restrict__ Bt,
                                                  float* __restrict__ outp) {
  __shared__ __align__(16) bf16_t As[128 * 32];
  __shared__ __align__(16) bf16_t Bs[128 * 32];
  const int tid = threadIdx.x;
  const int m0 = blockIdx.y * 128, n0 = blockIdx.x * 128;
  const int lane = tid & 63, w = tid >> 6;
  const int wm = (w >> 1) * 64, wn = (w & 1) * 64;
  const int q = lane >> 4, r = lane & 15;
  f32x4 acc[4][4];
#pragma unroll
  for (int i = 0; i < 4; ++i)
#pragma unroll
    for (int j = 0; j < 4; ++j) acc[i][j] = (f32x4){0.f, 0.f, 0.f, 0.f};
  const bf16_t* Ap = A + (size_t)m0 * HID;
  const bf16_t* Bp = Bt + (size_t)n0 * HID;
  for (int k0 = 0; k0 < HID; k0 += 32) {
    stage_async(As, Ap + k0, HID, tid);
    stage_async(Bs, Bp + k0, HID, tid);
    __syncthreads();
    wave_mma<4, 4>(As, Bs, acc, wm, wn, lane);
    __syncthreads();
  }
#pragma unroll
  for (int i = 0; i < 4; ++i) {
#pragma unroll
    for (int t = 0; t < 4; ++t) {
      int row = m0 + wm + i * 16 + q * 4 + t;
#pragma unroll
      for (int j = 0; j < 4; ++j) {
        int col = n0 + wn + j * 16 + r;
        outp[(size_t)row * HID + col] = acc[i][j][t];
      }
    }
  }
}

// =============================================================================
extern "C" void kernel_launch(void* const* d_in, const int* in_sizes, int n_in,
                              void* d_out, int out_size, void* d_ws, size_t ws_size,
                              hipStream_t stream) {
  const float* hs   = (const float*)d_in[0];
  const float* cosb = (const float*)d_in[1];
  const float* sinb = (const float*)d_in[2];
  // d_in[3] attention_mask: causal structure recomputed from indices
  const float* Wq = (const float*)d_in[4];
  const float* bq = (const float*)d_in[5];
  const float* Wk = (const float*)d_in[6];
  const float* bk = (const float*)d_in[7];
  const float* Wv = (const float*)d_in[8];
  const float* bv = (const float*)d_in[9];
  const float* Wo = (const float*)d_in[10];

  float* out  = (float*)d_out;                // (B,S,HID)
  float* attn = out + (size_t)Bb * Ss * HID;  // (B,NH,S,S)

  char* wsp = (char*)d_ws;
  auto alloc = [&](size_t bytes) -> char* {
    char* p = wsp;
    wsp += (bytes + 255) & ~(size_t)255;
    return p;
  };
  bf16_t* hs_bf = (bf16_t*)alloc((size_t)Mrows * HID * 2);
  bf16_t* wqkv  = (bf16_t*)alloc((size_t)2560 * HID * 2);  // [Wq;Wk;Wv] bf16
  bf16_t* wo_bf = (bf16_t*)alloc((size_t)HID * NH * HD * 2);
  bf16_t* q_bf  = (bf16_t*)alloc((size_t)Mrows * NH * HD * 2);
  bf16_t* k_bf  = (bf16_t*)alloc((size_t)Bb * NKV * Ss * HD * 2);
  bf16_t* v_t   = (bf16_t*)alloc((size_t)Bb * NKV * Ss * HD * 2);
  bf16_t* ao_bf = (bf16_t*)alloc((size_t)Mrows * NH * HD * 2);
  float*  rs_ws = (float*)alloc((size_t)Bb * NH * Ss * 4);

  // 0) zero row-sum accumulators (ws is poisoned each launch)
  zero_kernel<<<(Bb * NH * Ss) / 256, 256, 0, stream>>>(rs_ws);

  // 1) fp32 -> bf16 converts (weights concatenated into wqkv)
  cvt_bf16_kernel<<<(Mrows * HID) / 2048, 256, 0, stream>>>(hs, hs_bf);
  cvt_bf16_kernel<<<(NH * HD * HID) / 2048, 256, 0, stream>>>(Wq, wqkv);
  cvt_bf16_kernel<<<(NKV * HD * HID) / 2048, 256, 0, stream>>>(Wk, wqkv + (size_t)2048 * HID);
  cvt_bf16_kernel<<<(NKV * HD * HID) / 2048, 256, 0, stream>>>(Wv, wqkv + (size_t)2304 * HID);
  cvt_bf16_kernel<<<(HID * NH * HD) / 2048, 256, 0, stream>>>(Wo, wo_bf);

  // 2) fused QKV projection + bias + RoPE + V-transpose
  proj_kernel<<<dim3(20, 32), 256, 0, stream>>>(hs_bf, wqkv, bq, bk, bv, cosb, sinb,
                                                q_bf, k_bf, v_t);

  // 3) pass 1: rowsums only (lower-triangle tiles, no P write)
  qs_kernel<<<dim3(16, 16, Bb * NH), 256, 0, stream>>>(q_bf, k_bf, rs_ws);

  // 4) pass 2: recompute QK, write normalized attn once (+ zero upper),
  //    fused PV -> attn_out
  spv_kernel<<<dim3(1, 16, Bb * NH), 256, 0, stream>>>(q_bf, k_bf, v_t, rs_ws,
                                                       attn, ao_bf);

  // 5) out = attn_out @ Wo^T
  out_kernel<<<dim3(16, 32), 256, 0, stream>>>(ao_bf, wo_bf, out);

  (void)in_sizes; (void)n_in; (void)out_size; (void)ws_size;
}

// Round 3
// 929.290 us; speedup vs baseline: 1.1606x; 1.0799x over previous
//
#include <hip/hip_runtime.h>
#include <hip/hip_bf16.h>
#include <cstdint>

// Problem constants
constexpr int Bb  = 2;
constexpr int Ss  = 2048;
constexpr int HID = 2048;
constexpr int NH  = 16;
constexpr int NKV = 2;
constexpr int HD  = 128;
constexpr int Mrows = Bb * Ss;                 // 4096 rows for projections
constexpr float SCALE = 0.08838834764831845f;  // 1/sqrt(128)

typedef __bf16 bf16_t;
typedef __attribute__((ext_vector_type(8))) __bf16 bf16x8;
typedef __attribute__((ext_vector_type(4))) __bf16 bf16x4;
typedef __attribute__((ext_vector_type(4))) float f32x4;

static __device__ __forceinline__ f32x4 mfma16(bf16x8 a, bf16x8 b, f32x4 c) {
  return __builtin_amdgcn_mfma_f32_16x16x32_bf16(a, b, c, 0, 0, 0);
}

// ---- async 128x32 bf16 tile staging via global_load_lds (16B per lane) ------
// LDS layout [row][32] contiguous; chunk c: row=c>>2, kcol=(c&3)*8.
// dst byte offset = c*16 = wave-uniform base + lane*16  (required HW pattern)
static __device__ __forceinline__ void stage_async(bf16_t* lds, const bf16_t* src,
                                                   int ld, int tid) {
#pragma unroll
  for (int it = 0; it < 2; ++it) {
    int c = tid + it * 256;
    int row = c >> 2, kc = c & 3;
    __builtin_amdgcn_global_load_lds(
        (const __attribute__((address_space(1))) void*)(src + (size_t)row * ld + kc * 8),
        (__attribute__((address_space(3))) void*)(lds + c * 8), 16, 0, 0);
  }
}

// ---------------- per-wave MFMA compute, templated wave shape ----------------
template <int IM, int JM>
static __device__ __forceinline__ void wave_mma(const bf16_t* As, const bf16_t* Bs,
                                                f32x4 (&acc)[IM][JM], int wm, int wn,
                                                int lane) {
  const int q = lane >> 4, r = lane & 15;
  bf16x8 a[IM], b[JM];
#pragma unroll
  for (int i = 0; i < IM; ++i)
    a[i] = *(const bf16x8*)(As + (wm + i * 16 + r) * 32 + q * 8);
#pragma unroll
  for (int j = 0; j < JM; ++j)
    b[j] = *(const bf16x8*)(Bs + (wn + j * 16 + r) * 32 + q * 8);
#pragma unroll
  for (int i = 0; i < IM; ++i)
#pragma unroll
    for (int j = 0; j < JM; ++j)
      acc[i][j] = mfma16(a[i], b[j], acc[i][j]);
}

// ------------------------------ small kernels --------------------------------
__global__ void cvt_bf16_kernel(const float* __restrict__ in, bf16_t* __restrict__ out) {
  size_t i = ((size_t)blockIdx.x * 256 + threadIdx.x) * 8;
  float4 a = *(const float4*)(in + i);
  float4 b = *(const float4*)(in + i + 4);
  bf16x8 v;
  v[0] = (__bf16)a.x; v[1] = (__bf16)a.y; v[2] = (__bf16)a.z; v[3] = (__bf16)a.w;
  v[4] = (__bf16)b.x; v[5] = (__bf16)b.y; v[6] = (__bf16)b.z; v[7] = (__bf16)b.w;
  *(bf16x8*)(out + i) = v;
}

// ------------- fused QKV projection + bias + RoPE/transpose epilogue ---------
// A: (4096, 2048) bf16 = hs. B: (2560, 2048) bf16 = [Wq; Wk; Wv].
// cols [0,2048): q -> rope -> q_bf (B,NH,S,HD)
// cols [2048,2304): k -> rope -> k_bf (B,NKV,S,HD)
// cols [2304,2560): v -> transposed -> v_t (B,NKV,HD,S)
// Wave partition: each wave 32 rows x 128 cols so RoPE partner (d^64) is
// acc[i][j^4][t] in the SAME lane (no cross-wave exchange needed).
__global__ __launch_bounds__(256) void proj_kernel(
    const bf16_t* __restrict__ A, const bf16_t* __restrict__ Bt,
    const float* __restrict__ bq, const float* __restrict__ bk,
    const float* __restrict__ bv, const float* __restrict__ cosb,
    const float* __restrict__ sinb, bf16_t* __restrict__ q_bf,
    bf16_t* __restrict__ k_bf, bf16_t* __restrict__ v_t) {
  __shared__ __align__(16) bf16_t As[128 * 32];
  __shared__ __align__(16) bf16_t Bs[128 * 32];
  const int tid = threadIdx.x;
  const int bx = blockIdx.x;
  const int m0 = blockIdx.y * 128, n0 = bx * 128;
  const int lane = tid & 63, w = tid >> 6;
  const int wm = w * 32;  // 32 rows x 128 cols per wave
  const int q = lane >> 4, r = lane & 15;
  f32x4 acc[2][8];
#pragma unroll
  for (int i = 0; i < 2; ++i)
#pragma unroll
    for (int j = 0; j < 8; ++j) acc[i][j] = (f32x4){0.f, 0.f, 0.f, 0.f};
  const bf16_t* Ap = A + (size_t)m0 * HID;
  const bf16_t* Bp = Bt + (size_t)n0 * HID;
  for (int k0 = 0; k0 < HID; k0 += 32) {
    stage_async(As, Ap + k0, HID, tid);
    stage_async(Bs, Bp + k0, HID, tid);
    __syncthreads();
    wave_mma<2, 8>(As, Bs, acc, wm, 0, lane);
    __syncthreads();
  }
  // block-uniform output mode
  const float* bias_base;
  int mode;  // 0=q, 1=k, 2=v
  int hh;
  if (bx < 16) { mode = 0; hh = bx; bias_base = bq + n0; }
  else if (bx < 18) { mode = 1; hh = bx - 16; bias_base = bk + (bx - 16) * 128; }
  else { mode = 2; hh = bx - 18; bias_base = bv + (bx - 18) * 128; }
  float bias_j[8];
#pragma unroll
  for (int j = 0; j < 8; ++j) bias_j[j] = bias_base[j * 16 + r];
  float e[2][8][4];
#pragma unroll
  for (int i = 0; i < 2; ++i)
#pragma unroll
    for (int j = 0; j < 8; ++j)
#pragma unroll
      for (int t = 0; t < 4; ++t) e[i][j][t] = acc[i][j][t] + bias_j[j];

  if (mode == 2) {
    // V: store transposed (B,NKV,HD,S); 4 consecutive s per lane -> 8B packs
#pragma unroll
    for (int i = 0; i < 2; ++i) {
      int s_base = m0 + wm + i * 16 + q * 4;
      int bI = s_base >> 11, s = s_base & 2047;
#pragma unroll
      for (int j = 0; j < 8; ++j) {
        int d = j * 16 + r;
        bf16x4 pk;
#pragma unroll
        for (int t = 0; t < 4; ++t) pk[t] = (__bf16)e[i][j][t];
        *(bf16x4*)(v_t + ((size_t)(bI * NKV + hh) * HD + d) * Ss + s) = pk;
      }
    }
  } else {
    bf16_t* dst_base = (mode == 0) ? q_bf : k_bf;
    const int nhv = (mode == 0) ? NH : NKV;
#pragma unroll
    for (int i = 0; i < 2; ++i) {
#pragma unroll
      for (int t = 0; t < 4; ++t) {
        int s_glob = m0 + wm + i * 16 + q * 4 + t;
        int bI = s_glob >> 11, s = s_glob & 2047;
        const float* cp = cosb + ((size_t)bI * Ss + s) * HD;
        const float* sp = sinb + ((size_t)bI * Ss + s) * HD;
        bf16_t* dst = dst_base + ((size_t)(bI * nhv + hh) * Ss + s) * HD;
#pragma unroll
        for (int j = 0; j < 8; ++j) {
          int d = j * 16 + r;
          float c = cp[d], sn = sp[d];
          float p = e[i][j ^ 4][t];
          float o = e[i][j][t] * c + ((j < 4) ? -p : p) * sn;
          dst[d] = (__bf16)o;
        }
      }
    }
  }
}

// ---- fused two-sweep attention: rowsum sweep + (QK, normalize, PV) sweep ----
// One block per (row-strip mt, head bh), Q strip in registers (reused by both
// sweeps). Balanced grid remap: blocks p and p+256 (same CU under round-robin,
// 2 blocks/CU co-resident) get complementary mt and 15-mt -> 17 tiles/CU/sweep.
// LDS: Ks 32KB (time-shared K/V) + Ps 34.8KB (P transpose, +8 pad) -> 2 blk/CU.
__global__ __launch_bounds__(256, 2) void spv_kernel(
    const bf16_t* __restrict__ qb, const bf16_t* __restrict__ kb,
    const bf16_t* __restrict__ vt, float* __restrict__ attn,
    bf16_t* __restrict__ ao) {
  // balanced (bh, mt) from 1D grid
  const int bid = blockIdx.x;
  const int slot = bid >> 8, p = bid & 255;
  const int bh = p >> 3;
  const int m3 = p & 7;
  const int mt = slot ? (15 - m3) : m3;
  const int b = bh >> 4, h = bh & 15, kv = h >> 3;

  __shared__ __align__(16) bf16_t Ks[4][128 * 32];  // K or V slices (time-shared)
  __shared__ __align__(16) bf16_t Ps[128 * 136];    // P transpose buf, +8 pad
  __shared__ float rs[128];                         // row sums
  const int tid = threadIdx.x;
  if (tid < 128) rs[tid] = 0.0f;
  const int lane = tid & 63, w = tid >> 6;
  const int wm = (w >> 1) * 64, wn = (w & 1) * 64;
  const int q = lane >> 4, r = lane & 15;

  // ---- Q strip (128 x 128) -> registers, staged through LDS for coalescing
  const bf16_t* Qp = qb + (size_t)bh * Ss * HD + (size_t)mt * 128 * HD;
#pragma unroll
  for (int s = 0; s < 4; ++s) stage_async(Ks[s], Qp + s * 32, HD, tid);
  __syncthreads();  // Q staged (also fences rs init)
  bf16x8 aq[4][4];
#pragma unroll
  for (int s = 0; s < 4; ++s)
#pragma unroll
    for (int i = 0; i < 4; ++i)
      aq[s][i] = *(const bf16x8*)(Ks[s] + (wm + i * 16 + r) * 32 + q * 8);
  __syncthreads();  // Ks free for K staging

  const bf16_t* Kp = kb + (size_t)(b * NKV + kv) * Ss * HD;
  const bf16_t* Vp = vt + (size_t)(b * NKV + kv) * HD * Ss;
  float* Arow = attn + ((size_t)bh * Ss + (size_t)mt * 128) * Ss;

  // ================= sweep 1: row sums of exp(QK^T * SCALE) =================
  float rp[4][4];
#pragma unroll
  for (int i = 0; i < 4; ++i)
#pragma unroll
    for (int t = 0; t < 4; ++t) rp[i][t] = 0.0f;
#pragma unroll
  for (int s = 0; s < 4; ++s) stage_async(Ks[s], Kp + s * 32, HD, tid);
  for (int kt = 0; kt <= mt; ++kt) {
    __syncthreads();  // K(kt) ready
    f32x4 acc[4][4];
#pragma unroll
    for (int i = 0; i < 4; ++i)
#pragma unroll
      for (int j = 0; j < 4; ++j) acc[i][j] = (f32x4){0.f, 0.f, 0.f, 0.f};
#pragma unroll
    for (int s = 0; s < 4; ++s) {
      bf16x8 bfr[4];
#pragma unroll
      for (int j = 0; j < 4; ++j)
        bfr[j] = *(const bf16x8*)(Ks[s] + (wn + j * 16 + r) * 32 + q * 8);
#pragma unroll
      for (int i = 0; i < 4; ++i)
#pragma unroll
        for (int j = 0; j < 4; ++j)
          acc[i][j] = mfma16(aq[s][i], bfr[j], acc[i][j]);
    }
    __syncthreads();  // Ks reads done
    if (kt < mt) {    // issue next K; latency hides under rowsum math
#pragma unroll
      for (int s = 0; s < 4; ++s)
        stage_async(Ks[s], Kp + (size_t)(kt + 1) * 128 * HD + s * 32, HD, tid);
    }
    const bool diag = (kt == mt);
#pragma unroll
    for (int i = 0; i < 4; ++i) {
#pragma unroll
      for (int t = 0; t < 4; ++t) {
        int row_l = wm + i * 16 + q * 4 + t;
#pragma unroll
        for (int j = 0; j < 4; ++j) {
          int col_l = wn + j * 16 + r;
          float ev = (diag && col_l > row_l) ? 0.0f : __expf(acc[i][j][t] * SCALE);
          rp[i][t] += ev;
        }
      }
    }
  }
  // reduce row partials across the 16 lanes sharing q (lane = q*16 + r)
#pragma unroll
  for (int off = 1; off < 16; off <<= 1)
#pragma unroll
    for (int i = 0; i < 4; ++i)
#pragma unroll
      for (int t = 0; t < 4; ++t) rp[i][t] += __shfl_xor(rp[i][t], off, 64);
  if (r == 0) {
#pragma unroll
    for (int i = 0; i < 4; ++i)
#pragma unroll
      for (int t = 0; t < 4; ++t)
        atomicAdd(&rs[wm + i * 16 + q * 4 + t], rp[i][t]);
  }
  // issue K(0) for sweep 2 (Ks safe: post-QK sync above drained reads)
#pragma unroll
  for (int s = 0; s < 4; ++s) stage_async(Ks[s], Kp + s * 32, HD, tid);
  __syncthreads();  // rs complete + K(0) ready
  float inv_my[4][4];
#pragma unroll
  for (int i = 0; i < 4; ++i)
#pragma unroll
    for (int t = 0; t < 4; ++t)
      inv_my[i][t] = 1.0f / rs[wm + i * 16 + q * 4 + t];

  // ===== sweep 2: recompute QK, write normalized attn once, fused PV ========
  f32x4 acc2[4][4];
#pragma unroll
  for (int i = 0; i < 4; ++i)
#pragma unroll
    for (int j = 0; j < 4; ++j) acc2[i][j] = (f32x4){0.f, 0.f, 0.f, 0.f};

  for (int kt = 0; kt <= mt; ++kt) {
    // K(kt) already staged + drained (pre-loop sync or loop-tail sync A)
    f32x4 acc[4][4];
#pragma unroll
    for (int i = 0; i < 4; ++i)
#pragma unroll
      for (int j = 0; j < 4; ++j) acc[i][j] = (f32x4){0.f, 0.f, 0.f, 0.f};
#pragma unroll
    for (int s = 0; s < 4; ++s) {
      bf16x8 bfr[4];
#pragma unroll
      for (int j = 0; j < 4; ++j)
        bfr[j] = *(const bf16x8*)(Ks[s] + (wn + j * 16 + r) * 32 + q * 8);
#pragma unroll
      for (int i = 0; i < 4; ++i)
#pragma unroll
        for (int j = 0; j < 4; ++j)
          acc[i][j] = mfma16(aq[s][i], bfr[j], acc[i][j]);
    }
    __syncthreads();  // [B] Ks reads done -> free for V
    // issue V(kt); latency hides under the exp/Ps phase
#pragma unroll
    for (int s = 0; s < 4; ++s)
      stage_async(Ks[s], Vp + kt * 128 + s * 32, Ss, tid);
    // ---- exp * inv -> acc (kept for deferred global store) + Ps bf16
    const bool diag = (kt == mt);
#pragma unroll
    for (int i = 0; i < 4; ++i) {
#pragma unroll
      for (int t = 0; t < 4; ++t) {
        int row_l = wm + i * 16 + q * 4 + t;
        float inv = inv_my[i][t];
#pragma unroll
        for (int j = 0; j < 4; ++j) {
          int col_l = wn + j * 16 + r;
          float ev = (diag && col_l > row_l)
                         ? 0.0f
                         : __expf(acc[i][j][t] * SCALE) * inv;
          acc[i][j][t] = ev;
          Ps[row_l * 136 + col_l] = (__bf16)ev;
        }
      }
    }
    __syncthreads();  // [C] V ready + Ps visible
    // ---- PV accumulate (A = P from LDS transpose buffer, B = V slices)
#pragma unroll
    for (int s = 0; s < 4; ++s) {
      bf16x8 ap[4], bv4[4];
#pragma unroll
      for (int i = 0; i < 4; ++i)
        ap[i] = *(const bf16x8*)(Ps + (wm + i * 16 + r) * 136 + s * 32 + q * 8);
#pragma unroll
      for (int j = 0; j < 4; ++j)
        bv4[j] = *(const bf16x8*)(Ks[s] + (wn + j * 16 + r) * 32 + q * 8);
#pragma unroll
      for (int i = 0; i < 4; ++i)
#pragma unroll
        for (int j = 0; j < 4; ++j)
          acc2[i][j] = mfma16(ap[i], bv4[j], acc2[i][j]);
    }
    __syncthreads();  // [D] V + Ps reads done -> Ks/Ps free
    if (kt < mt) {    // issue next K; overlaps deferred attn store below
#pragma unroll
      for (int s = 0; s < 4; ++s)
        stage_async(Ks[s], Kp + (size_t)(kt + 1) * 128 * HD + s * 32, HD, tid);
    }
    // ---- deferred attn fp32 store (off the LDS critical path)
#pragma unroll
    for (int i = 0; i < 4; ++i) {
#pragma unroll
      for (int t = 0; t < 4; ++t) {
        int row_l = wm + i * 16 + q * 4 + t;
        float* orow = Arow + (size_t)row_l * Ss + kt * 128;
#pragma unroll
        for (int j = 0; j < 4; ++j) orow[wn + j * 16 + r] = acc[i][j][t];
      }
    }
    if (kt < mt) __syncthreads();  // [A] next K ready
  }

  // ---- zero-fill strictly-upper region: cols [kmax, 2048) of 128 rows
  const int kmax = (mt + 1) * 128;
  const int width = Ss - kmax;
  if (width > 0) {
    const float4 z4 = {0.f, 0.f, 0.f, 0.f};
    for (int rr = 0; rr < 128; ++rr) {
      float* zp = Arow + (size_t)rr * Ss + kmax;
      for (int cc = tid * 4; cc < width; cc += 1024) *(float4*)(zp + cc) = z4;
    }
  }
  // ---- epilogue: attn_out (B,S,NH*HD) bf16
#pragma unroll
  for (int i = 0; i < 4; ++i) {
#pragma unroll
    for (int t = 0; t < 4; ++t) {
      int row = mt * 128 + wm + i * 16 + q * 4 + t;
#pragma unroll
      for (int j = 0; j < 4; ++j) {
        int col = wn + j * 16 + r;
        ao[(((size_t)b * Ss + row) * NH + h) * HD + col] = (__bf16)acc2[i][j][t];
      }
    }
  }
}

// ------------------------ out = attn_out @ Wo^T ------------------------------
__global__ __launch_bounds__(256) void out_kernel(const bf16_t* __restrict__ A,
                                                  const bf16_t* __restrict__ Bt,
                                                  float* __restrict__ outp) {
  __shared__ __align__(16) bf16_t As[128 * 32];
  __shared__ __align__(16) bf16_t Bs[128 * 32];
  const int tid = threadIdx.x;
  const int m0 = blockIdx.y * 128, n0 = blockIdx.x * 128;
  const int lane = tid & 63, w = tid >> 6;
  const int wm = (w >> 1) * 64, wn = (w & 1) * 64;
  const int q = lane >> 4, r = lane & 15;
  f32x4 acc[4][4];
#pragma unroll
  for (int i = 0; i < 4; ++i)
#pragma unroll
    for (int j = 0; j < 4; ++j) acc[i][j] = (f32x4){0.f, 0.f, 0.f, 0.f};
  const bf16_t* Ap = A + (size_t)m0 * HID;
  const bf16_t* Bp = Bt + (size_t)n0 * HID;
  for (int k0 = 0; k0 < HID; k0 += 32) {
    stage_async(As, Ap + k0, HID, tid);
    stage_async(Bs, Bp + k0, HID, tid);
    __syncthreads();
    wave_mma<4, 4>(As, Bs, acc, wm, wn, lane);
    __syncthreads();
  }
#pragma unroll
  for (int i = 0; i < 4; ++i) {
#pragma unroll
    for (int t = 0; t < 4; ++t) {
      int row = m0 + wm + i * 16 + q * 4 + t;
#pragma unroll
      for (int j = 0; j < 4; ++j) {
        int col = n0 + wn + j * 16 + r;
        outp[(size_t)row * HID + col] = acc[i][j][t];
      }
    }
  }
}

// =============================================================================
extern "C" void kernel_launch(void* const* d_in, const int* in_sizes, int n_in,
                              void* d_out, int out_size, void* d_ws, size_t ws_size,
                              hipStream_t stream) {
  const float* hs   = (const float*)d_in[0];
  const float* cosb = (const float*)d_in[1];
  const float* sinb = (const float*)d_in[2];
  // d_in[3] attention_mask: causal structure recomputed from indices
  const float* Wq = (const float*)d_in[4];
  const float* bq = (const float*)d_in[5];
  const float* Wk = (const float*)d_in[6];
  const float* bk = (const float*)d_in[7];
  const float* Wv = (const float*)d_in[8];
  const float* bv = (const float*)d_in[9];
  const float* Wo = (const float*)d_in[10];

  float* out  = (float*)d_out;                // (B,S,HID)
  float* attn = out + (size_t)Bb * Ss * HID;  // (B,NH,S,S)

  char* wsp = (char*)d_ws;
  auto alloc = [&](size_t bytes) -> char* {
    char* p = wsp;
    wsp += (bytes + 255) & ~(size_t)255;
    return p;
  };
  bf16_t* hs_bf = (bf16_t*)alloc((size_t)Mrows * HID * 2);
  bf16_t* wqkv  = (bf16_t*)alloc((size_t)2560 * HID * 2);  // [Wq;Wk;Wv] bf16
  bf16_t* wo_bf = (bf16_t*)alloc((size_t)HID * NH * HD * 2);
  bf16_t* q_bf  = (bf16_t*)alloc((size_t)Mrows * NH * HD * 2);
  bf16_t* k_bf  = (bf16_t*)alloc((size_t)Bb * NKV * Ss * HD * 2);
  bf16_t* v_t   = (bf16_t*)alloc((size_t)Bb * NKV * Ss * HD * 2);
  bf16_t* ao_bf = (bf16_t*)alloc((size_t)Mrows * NH * HD * 2);

  // 1) fp32 -> bf16 converts (weights concatenated into wqkv)
  cvt_bf16_kernel<<<(Mrows * HID) / 2048, 256, 0, stream>>>(hs, hs_bf);
  cvt_bf16_kernel<<<(NH * HD * HID) / 2048, 256, 0, stream>>>(Wq, wqkv);
  cvt_bf16_kernel<<<(NKV * HD * HID) / 2048, 256, 0, stream>>>(Wk, wqkv + (size_t)2048 * HID);
  cvt_bf16_kernel<<<(NKV * HD * HID) / 2048, 256, 0, stream>>>(Wv, wqkv + (size_t)2304 * HID);
  cvt_bf16_kernel<<<(HID * NH * HD) / 2048, 256, 0, stream>>>(Wo, wo_bf);

  // 2) fused QKV projection + bias + RoPE + V-transpose
  proj_kernel<<<dim3(20, 32), 256, 0, stream>>>(hs_bf, wqkv, bq, bk, bv, cosb, sinb,
                                                q_bf, k_bf, v_t);

  // 3) fused two-sweep attention: rowsums + (QK, normalize-write, PV)
  spv_kernel<<<dim3(512), 256, 0, stream>>>(q_bf, k_bf, v_t, attn, ao_bf);

  // 4) out = attn_out @ Wo^T
  out_kernel<<<dim3(16, 32), 256, 0, stream>>>(ao_bf, wo_bf, out);

  (void)in_sizes; (void)n_in; (void)out_size; (void)ws_size;
}